// Round 1
// baseline (2285.998 us; speedup 1.0000x reference)
//
#include <hip/hip_runtime.h>
#include <math.h>

#define DEV __device__ __forceinline__

DEV float geluf(float x){ return 0.5f*x*(1.0f+erff(x*0.7071067811865476f)); }
DEV float siluf(float x){ return x/(1.0f+expf(-x)); }
DEV float softplusf(float x){ return fmaxf(x,0.0f)+log1pf(expf(-fabsf(x))); }

// ---------------- conv1: (8,12,4096) -> (8,192,2048), k=5 s=2 p=2, gelu+bn ----------------
__global__ void conv1_k(const float* __restrict__ x, const float* __restrict__ w,
                        const float* __restrict__ bias,
                        const float* __restrict__ g, const float* __restrict__ bb,
                        const float* __restrict__ m, const float* __restrict__ v,
                        float* __restrict__ out){
  int t  = blockIdx.x*256 + threadIdx.x;   // 0..2047
  int og = blockIdx.y;                     // 24 groups of 8 outputs
  int b  = blockIdx.z;
  const float* xb = x + (size_t)b*12*4096;
  float acc[8];
  #pragma unroll
  for(int oo=0;oo<8;++oo) acc[oo] = bias[og*8+oo];
  for(int i=0;i<12;++i){
    float xv[5];
    #pragma unroll
    for(int k=0;k<5;++k){
      int src = 2*t + k - 2;
      xv[k] = (src>=0 && src<4096) ? xb[i*4096+src] : 0.0f;
    }
    #pragma unroll
    for(int oo=0;oo<8;++oo){
      const float* wr = w + (size_t)(og*8+oo)*60 + i*5;
      #pragma unroll
      for(int k=0;k<5;++k) acc[oo] = fmaf(wr[k], xv[k], acc[oo]);
    }
  }
  #pragma unroll
  for(int oo=0;oo<8;++oo){
    int o = og*8+oo;
    float y = geluf(acc[oo]);
    float sc = g[o]*rsqrtf(v[o]+1e-5f);
    y = (y-m[o])*sc + bb[o];
    out[(size_t)b*192*2048 + (size_t)o*2048 + t] = y;
  }
}

// ---------------- conv2: (8,192,2048) -> (8,384,1024), k=3 s=2 p=1, gelu+bn ----------------
__global__ void conv2_k(const float* __restrict__ x, const float* __restrict__ w,
                        const float* __restrict__ bias,
                        const float* __restrict__ g, const float* __restrict__ bb,
                        const float* __restrict__ m, const float* __restrict__ v,
                        float* __restrict__ out){
  int t  = blockIdx.x*256 + threadIdx.x;   // 0..1023
  int og = blockIdx.y;                     // 48 groups of 8
  int b  = blockIdx.z;
  const float* xb = x + (size_t)b*192*2048;
  float acc[8];
  #pragma unroll
  for(int oo=0;oo<8;++oo) acc[oo] = bias[og*8+oo];
  int t2 = 2*t;
  for(int i=0;i<192;++i){
    const float* xr = xb + (size_t)i*2048;
    float x0 = (t2-1>=0) ? xr[t2-1] : 0.0f;
    float x1 = xr[t2];
    float x2 = xr[t2+1];
    #pragma unroll
    for(int oo=0;oo<8;++oo){
      const float* wr = w + (size_t)(og*8+oo)*576 + i*3;
      acc[oo] = fmaf(wr[0],x0,acc[oo]);
      acc[oo] = fmaf(wr[1],x1,acc[oo]);
      acc[oo] = fmaf(wr[2],x2,acc[oo]);
    }
  }
  #pragma unroll
  for(int oo=0;oo<8;++oo){
    int o = og*8+oo;
    float y = geluf(acc[oo]);
    float sc = g[o]*rsqrtf(v[o]+1e-5f);
    y = (y-m[o])*sc + bb[o];
    out[(size_t)b*384*1024 + (size_t)o*1024 + t] = y;
  }
}

// ---------------- conv3: (8,384,1024) -> (8,768,1024), k=3 s=1 p=1, gelu+bn ----------------
__global__ void conv3_k(const float* __restrict__ x, const float* __restrict__ w,
                        const float* __restrict__ bias,
                        const float* __restrict__ g, const float* __restrict__ bb,
                        const float* __restrict__ m, const float* __restrict__ v,
                        float* __restrict__ out){
  int t  = blockIdx.x*256 + threadIdx.x;   // 0..1023
  int og = blockIdx.y;                     // 96 groups of 8
  int b  = blockIdx.z;
  const float* xb = x + (size_t)b*384*1024;
  float acc[8];
  #pragma unroll
  for(int oo=0;oo<8;++oo) acc[oo] = bias[og*8+oo];
  for(int i=0;i<384;++i){
    const float* xr = xb + (size_t)i*1024;
    float x0 = (t>0)    ? xr[t-1] : 0.0f;
    float x1 = xr[t];
    float x2 = (t<1023) ? xr[t+1] : 0.0f;
    #pragma unroll
    for(int oo=0;oo<8;++oo){
      const float* wr = w + (size_t)(og*8+oo)*1152 + i*3;
      acc[oo] = fmaf(wr[0],x0,acc[oo]);
      acc[oo] = fmaf(wr[1],x1,acc[oo]);
      acc[oo] = fmaf(wr[2],x2,acc[oo]);
    }
  }
  #pragma unroll
  for(int oo=0;oo<8;++oo){
    int o = og*8+oo;
    float y = geluf(acc[oo]);
    float sc = g[o]*rsqrtf(v[o]+1e-5f);
    y = (y-m[o])*sc + bb[o];
    out[(size_t)b*768*1024 + (size_t)o*1024 + t] = y;
  }
}

// ---------------- in_proj GEMM: zx[m][n] = sum_k h3[b][k][t] * W[n][k] ----------------
// M=8192 (m=b*1024+t), N=3340, K=768. 64x64 tile, Ktile=16, 4x4 per thread.
#define IPJ_N 3340
__global__ __launch_bounds__(256) void inproj_k(const float* __restrict__ A,
                                                const float* __restrict__ W,
                                                float* __restrict__ out){
  __shared__ float As[16][64];
  __shared__ float Bs[16][68];   // padded rows: write conflicts -> 2-way (free)
  const int tid = threadIdx.x;
  const int n0 = blockIdx.x*64;
  const int b  = blockIdx.y >> 4;
  const int t0 = (blockIdx.y & 15)*64;
  const int m0 = blockIdx.y*64;
  const float* Ab = A + (size_t)b*786432 + t0;
  float acc[4][4] = {};
  for(int k0=0;k0<768;k0+=16){
    #pragma unroll
    for(int l=0;l<4;++l){
      int idx = tid + l*256;
      int mm = idx & 63, kk = idx >> 6;
      As[kk][mm] = Ab[(size_t)(k0+kk)*1024 + mm];
    }
    #pragma unroll
    for(int l=0;l<4;++l){
      int idx = tid + l*256;
      int kk = idx & 15, nn = idx >> 4;
      int n = n0 + nn;
      Bs[kk][nn] = (n < IPJ_N) ? W[(size_t)n*768 + k0 + kk] : 0.0f;
    }
    __syncthreads();
    #pragma unroll
    for(int k=0;k<16;++k){
      float4 a  = *reinterpret_cast<const float4*>(&As[k][(tid>>4)*4]);
      float4 bq = *reinterpret_cast<const float4*>(&Bs[k][(tid&15)*4]);
      float av[4] = {a.x,a.y,a.z,a.w};
      float bv[4] = {bq.x,bq.y,bq.z,bq.w};
      #pragma unroll
      for(int i=0;i<4;++i)
        #pragma unroll
        for(int j=0;j<4;++j)
          acc[i][j] = fmaf(av[i], bv[j], acc[i][j]);
    }
    __syncthreads();
  }
  #pragma unroll
  for(int i=0;i<4;++i){
    int mrow = m0 + (tid>>4)*4 + i;
    int nc = n0 + (tid&15)*4;
    if(nc+3 < IPJ_N){
      float4 st = make_float4(acc[i][0],acc[i][1],acc[i][2],acc[i][3]);
      *reinterpret_cast<float4*>(&out[(size_t)mrow*IPJ_N + nc]) = st;
    } else {
      #pragma unroll
      for(int j=0;j<4;++j) if(nc+j < IPJ_N) out[(size_t)mrow*IPJ_N + nc + j] = acc[i][j];
    }
  }
}

// ---------------- depthwise causal conv k=4 + silu + split ----------------
__global__ void dwconv_k(const float* __restrict__ zx, const float* __restrict__ cw,
                         const float* __restrict__ cb, float* __restrict__ xs,
                         float* __restrict__ Bo, float* __restrict__ Co){
  int gid = blockIdx.x*256 + threadIdx.x;   // 8*1024*1792
  int c = gid % 1792;
  int m = gid / 1792;
  int t = m & 1023;
  float4 w4 = *reinterpret_cast<const float4*>(&cw[c*4]);
  float wv[4] = {w4.x,w4.y,w4.z,w4.w};
  float acc = cb[c];
  #pragma unroll
  for(int j=0;j<4;++j){
    int tt = t - 3 + j;
    if(tt >= 0) acc = fmaf(wv[j], zx[(size_t)(m-3+j)*3340 + 1536 + c], acc);
  }
  float val = siluf(acc);
  if(c < 1536)       xs[(size_t)m*1536 + c]        = val;
  else if(c < 1664)  Bo[(size_t)m*128 + (c-1536)]  = val;
  else               Co[(size_t)m*128 + (c-1664)]  = val;
}

// ---------------- dt = softplus(raw + bias); dA = exp(dt * -exp(A_log)) ----------------
__global__ void dt_k(const float* __restrict__ zx, const float* __restrict__ dt_bias,
                     const float* __restrict__ A_log, float* __restrict__ dt,
                     float* __restrict__ dA){
  int gid = blockIdx.x*256 + threadIdx.x;   // 98304
  int h = gid % 12;
  int m = gid / 12;
  float raw = zx[(size_t)m*3340 + 3328 + h] + dt_bias[h];
  float sp = softplusf(raw);
  dt[gid] = sp;
  dA[gid] = expf(sp * (-expf(A_log[h])));
}

// ---------------- SSM scan: block=(phalf,h,b), thread=(p_local, n-slice of 32) ----------------
__global__ __launch_bounds__(256) void scan_k(const float* __restrict__ xs,
    const float* __restrict__ Bm, const float* __restrict__ Cm,
    const float* __restrict__ dtb, const float* __restrict__ dAb,
    const float* __restrict__ Dv, float* __restrict__ ys){
  const int ph = blockIdx.x, h = blockIdx.y, b = blockIdx.z;
  const int tid = threadIdx.x;
  const int ng = tid & 3;        // n-group: n = ng*32..+31
  const int pl = tid >> 2;       // p_local 0..63
  __shared__ float lx[16][64], lB[16][144], lC[16][144], ly[16][64];
  __shared__ float ldt[16], ldA[16];
  float s[32];
  #pragma unroll
  for(int j=0;j<32;++j) s[j]=0.0f;
  const float Dh = Dv[h];
  const size_t mbase = (size_t)b*1024;
  for(int t0=0;t0<1024;t0+=16){
    for(int idx=tid; idx<1024; idx+=256){
      int tl = idx>>6, p = idx&63;
      lx[tl][p] = xs[(mbase+t0+tl)*1536 + h*128 + ph*64 + p];
    }
    for(int idx=tid; idx<2048; idx+=256){
      int tl = idx>>7, c = idx&127;
      int slot = (c>>5)*36 + (c&31);   // +4 pad per n-slice -> conflict-free reads
      lB[tl][slot] = Bm[(mbase+t0+tl)*128 + c];
      lC[tl][slot] = Cm[(mbase+t0+tl)*128 + c];
    }
    if(tid<16){
      ldt[tid] = dtb[(mbase+t0+tid)*12 + h];
      ldA[tid] = dAb[(mbase+t0+tid)*12 + h];
    }
    __syncthreads();
    #pragma unroll 2
    for(int tl=0; tl<16; ++tl){
      float dtv = ldt[tl], dav = ldA[tl];
      float c0 = dtv * lx[tl][pl];
      float y = 0.0f;
      #pragma unroll
      for(int jj=0;jj<8;++jj){
        float4 bq = *reinterpret_cast<const float4*>(&lB[tl][ng*36 + jj*4]);
        float4 cq = *reinterpret_cast<const float4*>(&lC[tl][ng*36 + jj*4]);
        s[jj*4+0] = fmaf(s[jj*4+0], dav, c0*bq.x); y = fmaf(s[jj*4+0], cq.x, y);
        s[jj*4+1] = fmaf(s[jj*4+1], dav, c0*bq.y); y = fmaf(s[jj*4+1], cq.y, y);
        s[jj*4+2] = fmaf(s[jj*4+2], dav, c0*bq.z); y = fmaf(s[jj*4+2], cq.z, y);
        s[jj*4+3] = fmaf(s[jj*4+3], dav, c0*bq.w); y = fmaf(s[jj*4+3], cq.w, y);
      }
      y += __shfl_xor(y,1);
      y += __shfl_xor(y,2);
      if(ng==0) ly[tl][pl] = y;
    }
    __syncthreads();
    for(int idx=tid; idx<1024; idx+=256){
      int tl = idx>>6, p = idx&63;
      ys[(mbase+t0+tl)*1536 + h*128 + ph*64 + p] = ly[tl][p] + Dh*lx[tl][p];
    }
    __syncthreads();
  }
}

// ---------------- gating: y*silu(z), RMSNorm, partitioned mean-accumulate ----------------
__global__ void gate_k(const float* __restrict__ ys, const float* __restrict__ zx,
                       const float* __restrict__ nw, float* __restrict__ ybp){
  int m = blockIdx.x;            // b*1024+t
  int b = m >> 10, t = m & 1023;
  int tid = threadIdx.x;
  float gvals[6];
  float ss = 0.0f;
  #pragma unroll
  for(int r=0;r<6;++r){
    int c = r*256 + tid;
    float yv = ys[(size_t)m*1536 + c];
    float zv = zx[(size_t)m*3340 + c];
    float gv = yv * siluf(zv);
    gvals[r] = gv;
    ss = fmaf(gv, gv, ss);
  }
  #pragma unroll
  for(int off=32;off;off>>=1) ss += __shfl_xor(ss, off);
  __shared__ float red[4];
  if((tid&63)==0) red[tid>>6] = ss;
  __syncthreads();
  float tot = red[0]+red[1]+red[2]+red[3];
  float scale = rsqrtf(tot*(1.0f/1536.0f) + 1e-5f);
  float* dst = ybp + ((size_t)(t&7)*8 + b)*1536;
  #pragma unroll
  for(int r=0;r<6;++r){
    int c = r*256 + tid;
    atomicAdd(&dst[c], gvals[r]*scale*nw[c]);
  }
}

// ---------------- ybar mean: sum 8 partitions, /1024 ----------------
__global__ void ybm_k(const float* __restrict__ ybp, float* __restrict__ ybm){
  int idx = blockIdx.x*256 + threadIdx.x;   // 12288
  float s = 0.0f;
  #pragma unroll
  for(int p=0;p<8;++p) s += ybp[(size_t)p*12288 + idx];
  ybm[idx] = s * (1.0f/1024.0f);
}

// ---------------- rep = ybar_mean @ out_proj^T (wave per output) ----------------
__global__ void rep_k(const float* __restrict__ ybm, const float* __restrict__ W,
                      float* __restrict__ rep){
  int wid  = (blockIdx.x<<2) + (threadIdx.x>>6);  // 6144 = 8*768
  int lane = threadIdx.x & 63;
  int b = wid / 768, o = wid % 768;
  const float* xr = ybm + (size_t)b*1536;
  const float* wr = W + (size_t)o*1536;
  float acc = 0.0f;
  for(int c=lane;c<1536;c+=64) acc = fmaf(xr[c], wr[c], acc);
  #pragma unroll
  for(int off=32;off;off>>=1) acc += __shfl_xor(acc, off);
  if(lane==0) rep[wid] = acc;
}

// ---------------- fc1 + bn + relu (wave per output) ----------------
__global__ void fc1_k(const float* __restrict__ rep, const float* __restrict__ W,
                      const float* __restrict__ bias, const float* __restrict__ g,
                      const float* __restrict__ bb, const float* __restrict__ m,
                      const float* __restrict__ v, float* __restrict__ out){
  int wid  = (blockIdx.x<<2) + (threadIdx.x>>6);  // 8192 = 8*1024
  int lane = threadIdx.x & 63;
  int b = wid >> 10, o = wid & 1023;
  const float* xr = rep + (size_t)b*768;
  const float* wr = W + (size_t)o*768;
  float acc = 0.0f;
  for(int c=lane;c<768;c+=64) acc = fmaf(xr[c], wr[c], acc);
  #pragma unroll
  for(int off=32;off;off>>=1) acc += __shfl_xor(acc, off);
  if(lane==0){
    float val = acc + bias[o];
    float sc = g[o]*rsqrtf(v[o]+1e-5f);
    val = (val - m[o])*sc + bb[o];
    out[wid] = fmaxf(val, 0.0f);
  }
}

// ---------------- fc2 (wave per output) ----------------
__global__ void fc2_k(const float* __restrict__ h1, const float* __restrict__ W,
                      const float* __restrict__ bias, float* __restrict__ out){
  int wid  = (blockIdx.x<<2) + (threadIdx.x>>6);  // 216 = 8*27
  int lane = threadIdx.x & 63;
  int b = wid / 27, o = wid % 27;
  const float* xr = h1 + (size_t)b*1024;
  const float* wr = W + (size_t)o*1024;
  float acc = 0.0f;
  for(int c=lane;c<1024;c+=64) acc = fmaf(xr[c], wr[c], acc);
  #pragma unroll
  for(int off=32;off;off>>=1) acc += __shfl_xor(acc, off);
  if(lane==0) out[wid] = acc + bias[o];
}

// ---------------- workspace layout (float offsets) ----------------
#define OFF_H1  0u            // 3,145,728
#define OFF_H2  3145728u      // 3,145,728
#define OFF_H3  6291456u      // 6,291,456
#define OFF_ZX  12582912u     // 27,361,280
#define OFF_XS  39944192u     // 12,582,912
#define OFF_B   52527104u     // 1,048,576
#define OFF_C   53575680u     // 1,048,576
#define OFF_DT  54624256u     // 98,304
#define OFF_DA  54722560u     // 98,304
#define OFF_YBP 54820864u     // 98,304
#define OFF_YBM 54919168u     // 12,288
#define OFF_REP 54931456u     // 6,144
#define OFF_FC1 54937600u     // 8,192
#define OFF_Y   0u            // y_ssm (12,582,912) reuses dead h1..h3 region

extern "C" void kernel_launch(void* const* d_in, const int* in_sizes, int n_in,
                              void* d_out, int out_size, void* d_ws, size_t ws_size,
                              hipStream_t stream){
  const float* x       = (const float*)d_in[0];
  const float* w1      = (const float*)d_in[1];
  const float* b1      = (const float*)d_in[2];
  const float* bn1g    = (const float*)d_in[3];
  const float* bn1b    = (const float*)d_in[4];
  const float* bn1m    = (const float*)d_in[5];
  const float* bn1v    = (const float*)d_in[6];
  const float* w2      = (const float*)d_in[7];
  const float* b2      = (const float*)d_in[8];
  const float* bn2g    = (const float*)d_in[9];
  const float* bn2b    = (const float*)d_in[10];
  const float* bn2m    = (const float*)d_in[11];
  const float* bn2v    = (const float*)d_in[12];
  const float* w3      = (const float*)d_in[13];
  const float* b3      = (const float*)d_in[14];
  const float* bn3g    = (const float*)d_in[15];
  const float* bn3b    = (const float*)d_in[16];
  const float* bn3m    = (const float*)d_in[17];
  const float* bn3v    = (const float*)d_in[18];
  const float* ipw     = (const float*)d_in[19];
  const float* convw   = (const float*)d_in[20];
  const float* convb   = (const float*)d_in[21];
  const float* dtbias  = (const float*)d_in[22];
  const float* Alog    = (const float*)d_in[23];
  const float* Dvec    = (const float*)d_in[24];
  const float* normw   = (const float*)d_in[25];
  const float* opw     = (const float*)d_in[26];
  const float* fc1w    = (const float*)d_in[27];
  const float* fc1b    = (const float*)d_in[28];
  const float* bncg    = (const float*)d_in[29];
  const float* bncb    = (const float*)d_in[30];
  const float* bncm    = (const float*)d_in[31];
  const float* bncv    = (const float*)d_in[32];
  const float* fc2w    = (const float*)d_in[33];
  const float* fc2b    = (const float*)d_in[34];

  float* ws  = (float*)d_ws;
  float* h1  = ws + OFF_H1;
  float* h2  = ws + OFF_H2;
  float* h3  = ws + OFF_H3;
  float* zx  = ws + OFF_ZX;
  float* xsb = ws + OFF_XS;
  float* Bb  = ws + OFF_B;
  float* Cb  = ws + OFF_C;
  float* dtb = ws + OFF_DT;
  float* dAb = ws + OFF_DA;
  float* ybp = ws + OFF_YBP;
  float* ybm = ws + OFF_YBM;
  float* rep = ws + OFF_REP;
  float* f1b = ws + OFF_FC1;
  float* yb  = ws + OFF_Y;     // reuses h1..h3 after in_proj
  float* outp = (float*)d_out;

  hipMemsetAsync(ybp, 0, 98304*sizeof(float), stream);

  conv1_k<<<dim3(8,24,8),  256, 0, stream>>>(x,  w1, b1, bn1g, bn1b, bn1m, bn1v, h1);
  conv2_k<<<dim3(4,48,8),  256, 0, stream>>>(h1, w2, b2, bn2g, bn2b, bn2m, bn2v, h2);
  conv3_k<<<dim3(4,96,8),  256, 0, stream>>>(h2, w3, b3, bn3g, bn3b, bn3m, bn3v, h3);
  inproj_k<<<dim3(53,128), 256, 0, stream>>>(h3, ipw, zx);
  dwconv_k<<<57344, 256, 0, stream>>>(zx, convw, convb, xsb, Bb, Cb);
  dt_k<<<384, 256, 0, stream>>>(zx, dtbias, Alog, dtb, dAb);
  scan_k<<<dim3(2,12,8), 256, 0, stream>>>(xsb, Bb, Cb, dtb, dAb, Dvec, yb);
  gate_k<<<8192, 256, 0, stream>>>(yb, zx, normw, ybp);
  ybm_k<<<48, 256, 0, stream>>>(ybp, ybm);
  rep_k<<<1536, 256, 0, stream>>>(ybm, opw, rep);
  fc1_k<<<2048, 256, 0, stream>>>(rep, fc1w, fc1b, bncg, bncb, bncm, bncv, f1b);
  fc2_k<<<54, 256, 0, stream>>>(f1b, fc2w, fc2b, outp);
}

// Round 4
// 1176.004 us; speedup vs baseline: 1.9439x; 1.9439x over previous
//
#include <hip/hip_runtime.h>
#include <math.h>

#define DEV __device__ __forceinline__

DEV float geluf(float x){ return 0.5f*x*(1.0f+erff(x*0.7071067811865476f)); }
DEV float siluf(float x){ return x/(1.0f+expf(-x)); }
DEV float softplusf(float x){ return fmaxf(x,0.0f)+log1pf(expf(-fabsf(x))); }
DEV unsigned short f2bf(float f){
  unsigned int u = __float_as_uint(f);
  unsigned int r = (u + 0x7fffu + ((u>>16)&1u)) >> 16;
  return (unsigned short)r;
}

typedef __attribute__((ext_vector_type(8))) short short8;
typedef __attribute__((ext_vector_type(4))) float f32x4;

// ---------------- conv1: (8,12,4096) -> (8,192,2048), k=5 s=2 p=2, gelu+bn ----------------
__global__ void conv1_k(const float* __restrict__ x, const float* __restrict__ w,
                        const float* __restrict__ bias,
                        const float* __restrict__ g, const float* __restrict__ bb,
                        const float* __restrict__ m, const float* __restrict__ v,
                        float* __restrict__ out){
  int t  = blockIdx.x*256 + threadIdx.x;
  int og = blockIdx.y;
  int b  = blockIdx.z;
  const float* xb = x + (size_t)b*12*4096;
  float acc[8];
  #pragma unroll
  for(int oo=0;oo<8;++oo) acc[oo] = bias[og*8+oo];
  for(int i=0;i<12;++i){
    float xv[5];
    #pragma unroll
    for(int k=0;k<5;++k){
      int src = 2*t + k - 2;
      xv[k] = (src>=0 && src<4096) ? xb[i*4096+src] : 0.0f;
    }
    #pragma unroll
    for(int oo=0;oo<8;++oo){
      const float* wr = w + (size_t)(og*8+oo)*60 + i*5;
      #pragma unroll
      for(int k=0;k<5;++k) acc[oo] = fmaf(wr[k], xv[k], acc[oo]);
    }
  }
  #pragma unroll
  for(int oo=0;oo<8;++oo){
    int o = og*8+oo;
    float y = geluf(acc[oo]);
    float sc = g[o]*rsqrtf(v[o]+1e-5f);
    y = (y-m[o])*sc + bb[o];
    out[(size_t)b*192*2048 + (size_t)o*2048 + t] = y;
  }
}

// ---------------- conv2 ----------------
__global__ void conv2_k(const float* __restrict__ x, const float* __restrict__ w,
                        const float* __restrict__ bias,
                        const float* __restrict__ g, const float* __restrict__ bb,
                        const float* __restrict__ m, const float* __restrict__ v,
                        float* __restrict__ out){
  int t  = blockIdx.x*256 + threadIdx.x;
  int og = blockIdx.y;
  int b  = blockIdx.z;
  const float* xb = x + (size_t)b*192*2048;
  float acc[8];
  #pragma unroll
  for(int oo=0;oo<8;++oo) acc[oo] = bias[og*8+oo];
  int t2 = 2*t;
  for(int i=0;i<192;++i){
    const float* xr = xb + (size_t)i*2048;
    float x0 = (t2-1>=0) ? xr[t2-1] : 0.0f;
    float x1 = xr[t2];
    float x2 = xr[t2+1];
    #pragma unroll
    for(int oo=0;oo<8;++oo){
      const float* wr = w + (size_t)(og*8+oo)*576 + i*3;
      acc[oo] = fmaf(wr[0],x0,acc[oo]);
      acc[oo] = fmaf(wr[1],x1,acc[oo]);
      acc[oo] = fmaf(wr[2],x2,acc[oo]);
    }
  }
  #pragma unroll
  for(int oo=0;oo<8;++oo){
    int o = og*8+oo;
    float y = geluf(acc[oo]);
    float sc = g[o]*rsqrtf(v[o]+1e-5f);
    y = (y-m[o])*sc + bb[o];
    out[(size_t)b*384*1024 + (size_t)o*1024 + t] = y;
  }
}

// ---------------- conv3 ----------------
__global__ void conv3_k(const float* __restrict__ x, const float* __restrict__ w,
                        const float* __restrict__ bias,
                        const float* __restrict__ g, const float* __restrict__ bb,
                        const float* __restrict__ m, const float* __restrict__ v,
                        float* __restrict__ out){
  int t  = blockIdx.x*256 + threadIdx.x;
  int og = blockIdx.y;
  int b  = blockIdx.z;
  const float* xb = x + (size_t)b*384*1024;
  float acc[8];
  #pragma unroll
  for(int oo=0;oo<8;++oo) acc[oo] = bias[og*8+oo];
  for(int i=0;i<384;++i){
    const float* xr = xb + (size_t)i*1024;
    float x0 = (t>0)    ? xr[t-1] : 0.0f;
    float x1 = xr[t];
    float x2 = (t<1023) ? xr[t+1] : 0.0f;
    #pragma unroll
    for(int oo=0;oo<8;++oo){
      const float* wr = w + (size_t)(og*8+oo)*1152 + i*3;
      acc[oo] = fmaf(wr[0],x0,acc[oo]);
      acc[oo] = fmaf(wr[1],x1,acc[oo]);
      acc[oo] = fmaf(wr[2],x2,acc[oo]);
    }
  }
  #pragma unroll
  for(int oo=0;oo<8;++oo){
    int o = og*8+oo;
    float y = geluf(acc[oo]);
    float sc = g[o]*rsqrtf(v[o]+1e-5f);
    y = (y-m[o])*sc + bb[o];
    out[(size_t)b*768*1024 + (size_t)o*1024 + t] = y;
  }
}

// ---------------- transpose h3 [b][k][t] fp32 -> Ab [b][t][k] bf16 ----------------
__global__ void xposeA_k(const float* __restrict__ h3, unsigned short* __restrict__ Ab){
  __shared__ float tile[32][33];
  int t0 = blockIdx.x*32, k0 = blockIdx.y*32, b = blockIdx.z;
  int c = threadIdx.x & 31, r4 = threadIdx.x >> 5;
  const float* src = h3 + (size_t)b*786432;
  #pragma unroll
  for(int i=0;i<4;++i){ int r = r4 + i*8; tile[r][c] = src[(size_t)(k0+r)*1024 + t0 + c]; }
  __syncthreads();
  unsigned short* dst = Ab + (size_t)b*786432;
  #pragma unroll
  for(int i=0;i<4;++i){ int r = r4 + i*8;
    dst[(size_t)(t0+r)*768 + k0 + c] = f2bf(tile[c][r]);
  }
}

// ---------------- W rows 0..3327 fp32 -> bf16 ----------------
__global__ void wconv_k(const float* __restrict__ W, unsigned short* __restrict__ Wb){
  int i = (blockIdx.x*256 + threadIdx.x)*4;
  if(i < 2555904){
    float4 v = *reinterpret_cast<const float4*>(&W[i]);
    Wb[i+0] = f2bf(v.x); Wb[i+1] = f2bf(v.y); Wb[i+2] = f2bf(v.z); Wb[i+3] = f2bf(v.w);
  }
}

// ---------------- in_proj MFMA: out[m][n] = sum_k A[m][k]*W[n][k]; M=8192 N=3328 K=768 ----------------
__global__ __launch_bounds__(256) void inproj_mfma(const unsigned short* __restrict__ A,
                                                   const unsigned short* __restrict__ B,
                                                   float* __restrict__ out){
  __shared__ unsigned short As[4096], Bs[4096];   // 128 rows x 32 k, 16B-unit xor swizzle
  const int tid = threadIdx.x;
  const int lane = tid & 63, wave = tid >> 6;
  const int wm = wave & 1, wn = wave >> 1;
  const int m0 = blockIdx.y*128, n0 = blockIdx.x*128;
  f32x4 acc[4][4];
  #pragma unroll
  for(int i=0;i<4;++i)
    #pragma unroll
    for(int j=0;j<4;++j) acc[i][j] = (f32x4){0.f,0.f,0.f,0.f};
  const int u0 = tid, u1 = tid + 256;
  const int r0 = u0>>2, kl0 = (u0&3) ^ ((r0>>1)&3);
  const int r1 = u1>>2, kl1 = (u1&3) ^ ((r1>>1)&3);
  const int kg = lane>>4, ml = lane&15;
  for(int k0=0;k0<768;k0+=32){
    short8 a0 = *reinterpret_cast<const short8*>(A + (size_t)(m0+r0)*768 + k0 + kl0*8);
    short8 a1 = *reinterpret_cast<const short8*>(A + (size_t)(m0+r1)*768 + k0 + kl1*8);
    short8 b0 = *reinterpret_cast<const short8*>(B + (size_t)(n0+r0)*768 + k0 + kl0*8);
    short8 b1 = *reinterpret_cast<const short8*>(B + (size_t)(n0+r1)*768 + k0 + kl1*8);
    __syncthreads();
    *reinterpret_cast<short8*>(As + u0*8) = a0;
    *reinterpret_cast<short8*>(As + u1*8) = a1;
    *reinterpret_cast<short8*>(Bs + u0*8) = b0;
    *reinterpret_cast<short8*>(Bs + u1*8) = b1;
    __syncthreads();
    short8 af[4], bfr[4];
    #pragma unroll
    for(int f=0;f<4;++f){
      int row = wm*64 + f*16 + ml;
      int un  = row*4 + (kg ^ ((row>>1)&3));
      af[f] = *reinterpret_cast<const short8*>(As + un*8);
      int rowb = wn*64 + f*16 + ml;
      int ub   = rowb*4 + (kg ^ ((rowb>>1)&3));
      bfr[f] = *reinterpret_cast<const short8*>(Bs + ub*8);
    }
    #pragma unroll
    for(int i=0;i<4;++i)
      #pragma unroll
      for(int j=0;j<4;++j)
        acc[i][j] = __builtin_amdgcn_mfma_f32_16x16x32_bf16(af[i], bfr[j], acc[i][j], 0, 0, 0);
  }
  #pragma unroll
  for(int i=0;i<4;++i){
    int rb = m0 + wm*64 + i*16 + kg*4;
    #pragma unroll
    for(int j=0;j<4;++j){
      int col = n0 + wn*64 + j*16 + ml;
      #pragma unroll
      for(int r=0;r<4;++r)
        out[(size_t)(rb+r)*3340 + col] = acc[i][j][r];
    }
  }
}

// ---------------- dt raw GEMM (fp32): dtraw[m][h] = sum_k h3[b][k][t]*W[3328+h][k] ----------------
__global__ __launch_bounds__(256) void dtgemm_k(const float* __restrict__ h3,
    const float* __restrict__ W, float* __restrict__ dtraw){
  __shared__ float Ws[128][12];
  int mt = blockIdx.x, ks = blockIdx.y;
  int tid = threadIdx.x;
  for(int idx=tid; idx<1536; idx+=256){
    int k = idx/12, hh = idx - k*12;
    Ws[k][hh] = W[(size_t)(3328+hh)*768 + ks*128 + k];
  }
  __syncthreads();
  int ml = tid & 127, hg = tid >> 7;
  int m = mt*128 + ml; int b = m>>10, t = m&1023;
  const float* ap = h3 + (size_t)b*786432 + (size_t)ks*128*1024 + t;
  float acc[6] = {0,0,0,0,0,0};
  for(int k=0;k<128;++k){
    float a = ap[(size_t)k*1024];
    #pragma unroll
    for(int j=0;j<6;++j) acc[j] = fmaf(a, Ws[k][hg*6+j], acc[j]);
  }
  #pragma unroll
  for(int j=0;j<6;++j) atomicAdd(&dtraw[(size_t)m*12 + hg*6 + j], acc[j]);
}

// ---------------- dt finalize: softplus + dA ----------------
__global__ void dtfin_k(const float* __restrict__ dtraw, const float* __restrict__ dt_bias,
                        const float* __restrict__ A_log, float* __restrict__ dt,
                        float* __restrict__ dA){
  int gid = blockIdx.x*256 + threadIdx.x;   // 98304
  int h = gid % 12;
  float raw = dtraw[gid] + dt_bias[h];
  float sp = softplusf(raw);
  dt[gid] = sp;
  dA[gid] = expf(sp * (-expf(A_log[h])));
}

// ---------------- depthwise causal conv k=4 + silu + split ----------------
__global__ void dwconv_k(const float* __restrict__ zx, const float* __restrict__ cw,
                         const float* __restrict__ cb, float* __restrict__ xs,
                         float* __restrict__ Bo, float* __restrict__ Co){
  int gid = blockIdx.x*256 + threadIdx.x;
  int c = gid % 1792;
  int m = gid / 1792;
  int t = m & 1023;
  float4 w4 = *reinterpret_cast<const float4*>(&cw[c*4]);
  float wv[4] = {w4.x,w4.y,w4.z,w4.w};
  float acc = cb[c];
  #pragma unroll
  for(int j=0;j<4;++j){
    int tt = t - 3 + j;
    if(tt >= 0) acc = fmaf(wv[j], zx[(size_t)(m-3+j)*3340 + 1536 + c], acc);
  }
  float val = siluf(acc);
  if(c < 1536)       xs[(size_t)m*1536 + c]        = val;
  else if(c < 1664)  Bo[(size_t)m*128 + (c-1536)]  = val;
  else               Co[(size_t)m*128 + (c-1664)]  = val;
}

// ---------------- per-chunk inclusive cumprod of dA ----------------
__global__ void cumda_k(const float* __restrict__ dA, float* __restrict__ cda){
  __shared__ float ld[1024];
  int bh = blockIdx.x; int b = bh/12, hh = bh - b*12;
  int tid = threadIdx.x;
  for(int i=tid;i<1024;i+=128) ld[i] = dA[((size_t)b*1024 + i)*12 + hh];
  __syncthreads();
  for(int c=0;c<8;++c){
    int base = c*128;
    for(int off=1;off<128;off<<=1){
      float v = ld[base+tid];
      if(tid>=off) v *= ld[base+tid-off];
      __syncthreads();
      ld[base+tid] = v;
      __syncthreads();
    }
  }
  for(int i=tid;i<1024;i+=128) cda[(size_t)bh*1024 + i] = ld[i];
}

// ---------------- SSM scan pass 1: per-chunk local scan (in-place ys over xs) ----------------
#define SSTEP(E, BQE, CQE) \
  s[0][jj*4+E] = fmaf(s[0][jj*4+E], dav, c0*BQE); y0 = fmaf(s[0][jj*4+E], CQE, y0); \
  s[1][jj*4+E] = fmaf(s[1][jj*4+E], dav, c1*BQE); y1 = fmaf(s[1][jj*4+E], CQE, y1); \
  s[2][jj*4+E] = fmaf(s[2][jj*4+E], dav, c2*BQE); y2 = fmaf(s[2][jj*4+E], CQE, y2); \
  s[3][jj*4+E] = fmaf(s[3][jj*4+E], dav, c3*BQE); y3 = fmaf(s[3][jj*4+E], CQE, y3);

__global__ __launch_bounds__(128) void scan_chunk_k(float* __restrict__ xs,
    const float* __restrict__ Bm, const float* __restrict__ Cm,
    const float* __restrict__ dtb, const float* __restrict__ dAb,
    const float* __restrict__ Dv, float* __restrict__ sfin){
  const int c = blockIdx.x, h = blockIdx.y, b = blockIdx.z;
  const int tid = threadIdx.x;
  const int ng = tid & 3, pg = tid >> 2;   // p = pg*4+i, n = ng*32+...
  __shared__ float lx[16][128], lB[16][144], lC[16][144], ly[16][128];
  __shared__ float ldt[16], lda_[16];
  float s[4][32];
  #pragma unroll
  for(int i=0;i<4;++i)
    #pragma unroll
    for(int j=0;j<32;++j) s[i][j]=0.f;
  const float Dh = Dv[h];
  const size_t mb = (size_t)b*1024 + (size_t)c*128;
  for(int t0=0;t0<128;t0+=16){
    for(int idx=tid; idx<2048; idx+=128){
      int tl = idx>>7, cc = idx&127;
      lx[tl][cc] = xs[(mb+t0+tl)*1536 + h*128 + cc];
      int slot = (cc>>5)*36 + (cc&31);
      lB[tl][slot] = Bm[(mb+t0+tl)*128 + cc];
      lC[tl][slot] = Cm[(mb+t0+tl)*128 + cc];
    }
    if(tid<16){
      ldt[tid]  = dtb[(mb+t0+tid)*12 + h];
      lda_[tid] = dAb[(mb+t0+tid)*12 + h];
    }
    __syncthreads();
    for(int tl=0; tl<16; ++tl){
      float dtv = ldt[tl], dav = lda_[tl];
      float4 xq = *reinterpret_cast<const float4*>(&lx[tl][pg*4]);
      float c0 = dtv*xq.x, c1 = dtv*xq.y, c2 = dtv*xq.z, c3 = dtv*xq.w;
      float y0=0.f,y1=0.f,y2=0.f,y3=0.f;
      #pragma unroll
      for(int jj=0;jj<8;++jj){
        float4 bq = *reinterpret_cast<const float4*>(&lB[tl][ng*36+jj*4]);
        float4 cq = *reinterpret_cast<const float4*>(&lC[tl][ng*36+jj*4]);
        SSTEP(0, bq.x, cq.x)
        SSTEP(1, bq.y, cq.y)
        SSTEP(2, bq.z, cq.z)
        SSTEP(3, bq.w, cq.w)
      }
      y0 += __shfl_xor(y0,1); y0 += __shfl_xor(y0,2);
      y1 += __shfl_xor(y1,1); y1 += __shfl_xor(y1,2);
      y2 += __shfl_xor(y2,1); y2 += __shfl_xor(y2,2);
      y3 += __shfl_xor(y3,1); y3 += __shfl_xor(y3,2);
      if(ng==0) *reinterpret_cast<float4*>(&ly[tl][pg*4]) = make_float4(y0,y1,y2,y3);
    }
    __syncthreads();
    for(int idx=tid; idx<2048; idx+=128){
      int tl = idx>>7, cc = idx&127;
      xs[(mb+t0+tl)*1536 + h*128 + cc] = ly[tl][cc] + Dh*lx[tl][cc];
    }
    __syncthreads();
  }
  // store local final state, [n][p] layout
  float* dst = sfin + ((size_t)(b*12+h)*8 + c)*16384;
  #pragma unroll
  for(int jj=0;jj<8;++jj)
    #pragma unroll
    for(int e=0;e<4;++e){
      int n = ng*32 + jj*4 + e;
      *reinterpret_cast<float4*>(&dst[(size_t)n*128 + pg*4]) =
        make_float4(s[0][jj*4+e], s[1][jj*4+e], s[2][jj*4+e], s[3][jj*4+e]);
    }
}

// ---------------- SSM scan pass 2: inter-chunk correction y += cumP * (C . S_init) ----------------
__global__ __launch_bounds__(256) void correct_k(const float* __restrict__ Cm,
    const float* __restrict__ cumdA, const float* __restrict__ sfin,
    float* __restrict__ ys){
  const int c = blockIdx.x + 1, h = blockIdx.y, b = blockIdx.z;
  const int tid = threadIdx.x;
  const size_t bh = (size_t)b*12 + h;
  __shared__ float Sl[16][128];
  __shared__ float Cl[16][132];
  __shared__ float cumP[128];
  __shared__ float coefs[8];
  if(tid==0){
    float cf = 1.f;
    for(int cp=c-1; cp>=0; --cp){
      coefs[cp] = cf;
      cf *= cumdA[bh*1024 + (size_t)cp*128 + 127];
    }
  }
  if(tid<128) cumP[tid] = cumdA[bh*1024 + (size_t)c*128 + tid];
  __syncthreads();
  const int tp = tid>>4, tt = tid&15;   // p-tile 8, t-tile 8
  float acc[8][8];
  #pragma unroll
  for(int i=0;i<8;++i)
    #pragma unroll
    for(int j=0;j<8;++j) acc[i][j]=0.f;
  const size_t mb = (size_t)b*1024 + (size_t)c*128;
  for(int n0=0;n0<128;n0+=16){
    {
      int kk = tid>>4, po = tid&15;
      float4 v0 = {0,0,0,0}, v1 = {0,0,0,0};
      for(int cp=0; cp<c; ++cp){
        const float* sp = sfin + ((bh*8 + cp)*16384) + (size_t)(n0+kk)*128 + po*8;
        float4 a0 = *reinterpret_cast<const float4*>(sp);
        float4 a1 = *reinterpret_cast<const float4*>(sp+4);
        float cf = coefs[cp];
        v0.x = fmaf(cf,a0.x,v0.x); v0.y = fmaf(cf,a0.y,v0.y);
        v0.z = fmaf(cf,a0.z,v0.z); v0.w = fmaf(cf,a0.w,v0.w);
        v1.x = fmaf(cf,a1.x,v1.x); v1.y = fmaf(cf,a1.y,v1.y);
        v1.z = fmaf(cf,a1.z,v1.z); v1.w = fmaf(cf,a1.w,v1.w);
      }
      *reinterpret_cast<float4*>(&Sl[kk][po*8])   = v0;
      *reinterpret_cast<float4*>(&Sl[kk][po*8+4]) = v1;
    }
    #pragma unroll
    for(int e=0;e<8;++e){
      int idx = tid*8 + e; int tl = idx>>4, kk = idx&15;
      Cl[kk][tl] = Cm[(mb + tl)*128 + n0 + kk];
    }
    __syncthreads();
    #pragma unroll
    for(int kk=0;kk<16;++kk){
      float4 sa = *reinterpret_cast<const float4*>(&Sl[kk][tp*8]);
      float4 sb = *reinterpret_cast<const float4*>(&Sl[kk][tp*8+4]);
      float4 ca = *reinterpret_cast<const float4*>(&Cl[kk][tt*8]);
      float4 cb = *reinterpret_cast<const float4*>(&Cl[kk][tt*8+4]);
      float sv[8] = {sa.x,sa.y,sa.z,sa.w,sb.x,sb.y,sb.z,sb.w};
      float cv[8] = {ca.x,ca.y,ca.z,ca.w,cb.x,cb.y,cb.z,cb.w};
      #pragma unroll
      for(int i=0;i<8;++i)
        #pragma unroll
        for(int j=0;j<8;++j) acc[i][j] = fmaf(sv[i], cv[j], acc[i][j]);
    }
    __syncthreads();
  }
  #pragma unroll
  for(int j=0;j<8;++j){
    int tl = tt*8 + j;
    float cp = cumP[tl];
    float* yp = ys + (mb + tl)*1536 + h*128 + tp*8;
    float4 y0 = *reinterpret_cast<float4*>(yp);
    float4 y1 = *reinterpret_cast<float4*>(yp+4);
    y0.x += cp*acc[0][j]; y0.y += cp*acc[1][j]; y0.z += cp*acc[2][j]; y0.w += cp*acc[3][j];
    y1.x += cp*acc[4][j]; y1.y += cp*acc[5][j]; y1.z += cp*acc[6][j]; y1.w += cp*acc[7][j];
    *reinterpret_cast<float4*>(yp)   = y0;
    *reinterpret_cast<float4*>(yp+4) = y1;
  }
}

// ---------------- gating: y*silu(z), RMSNorm, partitioned mean-accumulate ----------------
__global__ void gate_k(const float* __restrict__ ys, const float* __restrict__ zx,
                       const float* __restrict__ nw, float* __restrict__ ybp){
  int m = blockIdx.x;
  int b = m >> 10, t = m & 1023;
  int tid = threadIdx.x;
  float gvals[6];
  float ss = 0.0f;
  #pragma unroll
  for(int r=0;r<6;++r){
    int c = r*256 + tid;
    float yv = ys[(size_t)m*1536 + c];
    float zv = zx[(size_t)m*3340 + c];
    float gv = yv * siluf(zv);
    gvals[r] = gv;
    ss = fmaf(gv, gv, ss);
  }
  #pragma unroll
  for(int off=32;off;off>>=1) ss += __shfl_xor(ss, off);
  __shared__ float red[4];
  if((tid&63)==0) red[tid>>6] = ss;
  __syncthreads();
  float tot = red[0]+red[1]+red[2]+red[3];
  float scale = rsqrtf(tot*(1.0f/1536.0f) + 1e-5f);
  float* dst = ybp + ((size_t)(t&7)*8 + b)*1536;
  #pragma unroll
  for(int r=0;r<6;++r){
    int c = r*256 + tid;
    atomicAdd(&dst[c], gvals[r]*scale*nw[c]);
  }
}

__global__ void ybm_k(const float* __restrict__ ybp, float* __restrict__ ybm){
  int idx = blockIdx.x*256 + threadIdx.x;
  float s = 0.0f;
  #pragma unroll
  for(int p=0;p<8;++p) s += ybp[(size_t)p*12288 + idx];
  ybm[idx] = s * (1.0f/1024.0f);
}

__global__ void rep_k(const float* __restrict__ ybm, const float* __restrict__ W,
                      float* __restrict__ rep){
  int wid  = (blockIdx.x<<2) + (threadIdx.x>>6);
  int lane = threadIdx.x & 63;
  int b = wid / 768, o = wid % 768;
  const float* xr = ybm + (size_t)b*1536;
  const float* wr = W + (size_t)o*1536;
  float acc = 0.0f;
  for(int c=lane;c<1536;c+=64) acc = fmaf(xr[c], wr[c], acc);
  #pragma unroll
  for(int off=32;off;off>>=1) acc += __shfl_xor(acc, off);
  if(lane==0) rep[wid] = acc;
}

__global__ void fc1_k(const float* __restrict__ rep, const float* __restrict__ W,
                      const float* __restrict__ bias, const float* __restrict__ g,
                      const float* __restrict__ bb, const float* __restrict__ m,
                      const float* __restrict__ v, float* __restrict__ out){
  int wid  = (blockIdx.x<<2) + (threadIdx.x>>6);
  int lane = threadIdx.x & 63;
  int b = wid >> 10, o = wid & 1023;
  const float* xr = rep + (size_t)b*768;
  const float* wr = W + (size_t)o*768;
  float acc = 0.0f;
  for(int c=lane;c<768;c+=64) acc = fmaf(xr[c], wr[c], acc);
  #pragma unroll
  for(int off=32;off;off>>=1) acc += __shfl_xor(acc, off);
  if(lane==0){
    float val = acc + bias[o];
    float sc = g[o]*rsqrtf(v[o]+1e-5f);
    val = (val - m[o])*sc + bb[o];
    out[wid] = fmaxf(val, 0.0f);
  }
}

__global__ void fc2_k(const float* __restrict__ h1, const float* __restrict__ W,
                      const float* __restrict__ bias, float* __restrict__ out){
  int wid  = (blockIdx.x<<2) + (threadIdx.x>>6);
  int lane = threadIdx.x & 63;
  int b = wid / 27, o = wid % 27;
  const float* xr = h1 + (size_t)b*1024;
  const float* wr = W + (size_t)o*1024;
  float acc = 0.0f;
  for(int c=lane;c<1024;c+=64) acc = fmaf(xr[c], wr[c], acc);
  #pragma unroll
  for(int off=32;off;off>>=1) acc += __shfl_xor(acc, off);
  if(lane==0) out[wid] = acc + bias[o];
}

// ---------------- workspace layout (float offsets) ----------------
// Footprint is IDENTICAL to the round-1 passing run (54,945,792 floats,
// 219.78 MB): dtraw / cda / ybp have disjoint lifetimes and share one
// 98,304-float slot (OFF_SLOT98K), with stream-ordered memsets.
#define OFF_H1     0u
#define OFF_H2     3145728u
#define OFF_H3     6291456u
#define OFF_ZX     12582912u    // 27,361,280
#define OFF_XS     39944192u    // 12,582,912 (xs, then in-place ys)
#define OFF_B      52527104u    // 1,048,576
#define OFF_C      53575680u    // 1,048,576
#define OFF_DT     54624256u    // 98,304
#define OFF_DA     54722560u    // 98,304
#define OFF_SLOT98K 54820864u   // 98,304: dtraw -> cda -> ybp (sequential lifetimes)
#define OFF_YBM    54919168u    // 12,288
#define OFF_REP    54931456u    // 6,144
#define OFF_FC1    54937600u    // 8,192 ; end = 54,945,792 floats
// overlays (front region, after consumers finish):
#define OFF_ABF    0u           // ushort[6,291,456] (dead after inproj_mfma)
#define OFF_WB     3145728u     // ushort[2,555,904] (dead after inproj_mfma)
#define OFF_SFIN   0u           // float[12,582,912], written by scan (h1..h3/ABF/WB dead)

extern "C" void kernel_launch(void* const* d_in, const int* in_sizes, int n_in,
                              void* d_out, int out_size, void* d_ws, size_t ws_size,
                              hipStream_t stream){
  const float* x       = (const float*)d_in[0];
  const float* w1      = (const float*)d_in[1];
  const float* b1      = (const float*)d_in[2];
  const float* bn1g    = (const float*)d_in[3];
  const float* bn1b    = (const float*)d_in[4];
  const float* bn1m    = (const float*)d_in[5];
  const float* bn1v    = (const float*)d_in[6];
  const float* w2      = (const float*)d_in[7];
  const float* b2      = (const float*)d_in[8];
  const float* bn2g    = (const float*)d_in[9];
  const float* bn2b    = (const float*)d_in[10];
  const float* bn2m    = (const float*)d_in[11];
  const float* bn2v    = (const float*)d_in[12];
  const float* w3      = (const float*)d_in[13];
  const float* b3      = (const float*)d_in[14];
  const float* bn3g    = (const float*)d_in[15];
  const float* bn3b    = (const float*)d_in[16];
  const float* bn3m    = (const float*)d_in[17];
  const float* bn3v    = (const float*)d_in[18];
  const float* ipw     = (const float*)d_in[19];
  const float* convw   = (const float*)d_in[20];
  const float* convb   = (const float*)d_in[21];
  const float* dtbias  = (const float*)d_in[22];
  const float* Alog    = (const float*)d_in[23];
  const float* Dvec    = (const float*)d_in[24];
  const float* normw   = (const float*)d_in[25];
  const float* opw     = (const float*)d_in[26];
  const float* fc1w    = (const float*)d_in[27];
  const float* fc1b    = (const float*)d_in[28];
  const float* bncg    = (const float*)d_in[29];
  const float* bncb    = (const float*)d_in[30];
  const float* bncm    = (const float*)d_in[31];
  const float* bncv    = (const float*)d_in[32];
  const float* fc2w    = (const float*)d_in[33];
  const float* fc2b    = (const float*)d_in[34];

  float* ws   = (float*)d_ws;
  float* h1   = ws + OFF_H1;
  float* h2   = ws + OFF_H2;
  float* h3   = ws + OFF_H3;
  float* zx   = ws + OFF_ZX;
  float* xsb  = ws + OFF_XS;     // xs, then ys in-place
  float* Bb   = ws + OFF_B;
  float* Cb   = ws + OFF_C;
  float* dtb  = ws + OFF_DT;
  float* dAb  = ws + OFF_DA;
  float* slot = ws + OFF_SLOT98K; // dtraw, then cda, then ybp
  float* ybm  = ws + OFF_YBM;
  float* rep  = ws + OFF_REP;
  float* f1b  = ws + OFF_FC1;
  unsigned short* Abf = (unsigned short*)(ws + OFF_ABF);
  unsigned short* Wb  = (unsigned short*)(ws + OFF_WB);
  float* sfin = ws + OFF_SFIN;
  float* outp = (float*)d_out;

  conv1_k<<<dim3(8,24,8),  256, 0, stream>>>(x,  w1, b1, bn1g, bn1b, bn1m, bn1v, h1);
  conv2_k<<<dim3(4,48,8),  256, 0, stream>>>(h1, w2, b2, bn2g, bn2b, bn2m, bn2v, h2);
  conv3_k<<<dim3(4,96,8),  256, 0, stream>>>(h2, w3, b3, bn3g, bn3b, bn3m, bn3v, h3);
  xposeA_k<<<dim3(32,24,8),256, 0, stream>>>(h3, Abf);
  wconv_k<<<2496, 256, 0, stream>>>(ipw, Wb);
  inproj_mfma<<<dim3(26,64), 256, 0, stream>>>(Abf, Wb, zx);
  hipMemsetAsync(slot, 0, 98304*sizeof(float), stream);              // zero dtraw
  dtgemm_k<<<dim3(64,6), 256, 0, stream>>>(h3, ipw, slot);           // dtraw = slot
  dtfin_k<<<384, 256, 0, stream>>>(slot, dtbias, Alog, dtb, dAb);    // reads dtraw
  dwconv_k<<<57344, 256, 0, stream>>>(zx, convw, convb, xsb, Bb, Cb);
  cumda_k<<<96, 128, 0, stream>>>(dAb, slot);                        // cda = slot (full overwrite)
  scan_chunk_k<<<dim3(8,12,8), 128, 0, stream>>>(xsb, Bb, Cb, dtb, dAb, Dvec, sfin);
  correct_k<<<dim3(7,12,8), 256, 0, stream>>>(Cb, slot, sfin, xsb);  // reads cda
  hipMemsetAsync(slot, 0, 98304*sizeof(float), stream);              // zero ybp
  gate_k<<<8192, 256, 0, stream>>>(xsb, zx, normw, slot);            // ybp = slot
  ybm_k<<<48, 256, 0, stream>>>(slot, ybm);                          // reads ybp
  rep_k<<<1536, 256, 0, stream>>>(ybm, opw, rep);
  fc1_k<<<2048, 256, 0, stream>>>(rep, fc1w, fc1b, bncg, bncb, bncm, bncv, f1b);
  fc2_k<<<54, 256, 0, stream>>>(f1b, fc2w, fc2b, outp);
}

// Round 5
// 743.848 us; speedup vs baseline: 3.0732x; 1.5810x over previous
//
#include <hip/hip_runtime.h>
#include <math.h>

#define DEV __device__ __forceinline__

DEV float geluf(float x){ return 0.5f*x*(1.0f+erff(x*0.7071067811865476f)); }
DEV float siluf(float x){ return x/(1.0f+expf(-x)); }
DEV float softplusf(float x){ return fmaxf(x,0.0f)+log1pf(expf(-fabsf(x))); }
DEV unsigned short f2bf(float f){
  unsigned int u = __float_as_uint(f);
  unsigned int r = (u + 0x7fffu + ((u>>16)&1u)) >> 16;
  return (unsigned short)r;
}

typedef __attribute__((ext_vector_type(8))) short short8;
typedef __attribute__((ext_vector_type(4))) float f32x4;

// ---------------- conv1: (8,12,4096) -> (8,192,2048), k=5 s=2 p=2, gelu+bn ----------------
__global__ void conv1_k(const float* __restrict__ x, const float* __restrict__ w,
                        const float* __restrict__ bias,
                        const float* __restrict__ g, const float* __restrict__ bb,
                        const float* __restrict__ m, const float* __restrict__ v,
                        float* __restrict__ out){
  int t  = blockIdx.x*256 + threadIdx.x;
  int og = blockIdx.y;
  int b  = blockIdx.z;
  const float* xb = x + (size_t)b*12*4096;
  float acc[8];
  #pragma unroll
  for(int oo=0;oo<8;++oo) acc[oo] = bias[og*8+oo];
  for(int i=0;i<12;++i){
    float xv[5];
    #pragma unroll
    for(int k=0;k<5;++k){
      int src = 2*t + k - 2;
      xv[k] = (src>=0 && src<4096) ? xb[i*4096+src] : 0.0f;
    }
    #pragma unroll
    for(int oo=0;oo<8;++oo){
      const float* wr = w + (size_t)(og*8+oo)*60 + i*5;
      #pragma unroll
      for(int k=0;k<5;++k) acc[oo] = fmaf(wr[k], xv[k], acc[oo]);
    }
  }
  #pragma unroll
  for(int oo=0;oo<8;++oo){
    int o = og*8+oo;
    float y = geluf(acc[oo]);
    float sc = g[o]*rsqrtf(v[o]+1e-5f);
    y = (y-m[o])*sc + bb[o];
    out[(size_t)b*192*2048 + (size_t)o*2048 + t] = y;
  }
}

// ---------------- transpose-cast h1 [b][i][t] fp32 -> T1 [b*2048+t][192] bf16 ----------------
__global__ void xpose1_k(const float* __restrict__ h1, unsigned short* __restrict__ T1){
  __shared__ float tile[32][33];
  int t0 = blockIdx.x*32, i0 = blockIdx.y*32, b = blockIdx.z;
  int c = threadIdx.x & 31, r4 = threadIdx.x >> 5;
  const float* src = h1 + (size_t)b*393216;
  #pragma unroll
  for(int i=0;i<4;++i){ int r = r4 + i*8; tile[r][c] = src[(size_t)(i0+r)*2048 + t0 + c]; }
  __syncthreads();
  unsigned short* dst = T1 + (size_t)b*2048*192;
  #pragma unroll
  for(int i=0;i<4;++i){ int r = r4 + i*8;
    dst[(size_t)(t0+r)*192 + i0 + c] = f2bf(tile[c][r]);
  }
}

// ---------------- weight reorders: w[o][i][k] fp32 -> wr[o][k*C+i] bf16 ----------------
__global__ void wr2_k(const float* __restrict__ w, unsigned short* __restrict__ wr){
  int gid = blockIdx.x*256 + threadIdx.x;   // 384*576
  if(gid < 221184){
    int o = gid / 576, rem = gid - o*576, k = rem / 192, i = rem - k*192;
    wr[gid] = f2bf(w[(size_t)o*576 + i*3 + k]);
  }
}
__global__ void wr3_k(const float* __restrict__ w, unsigned short* __restrict__ wr){
  int gid = blockIdx.x*256 + threadIdx.x;   // 768*1152
  if(gid < 884736){
    int o = gid / 1152, rem = gid - o*1152, k = rem / 384, i = rem - k*384;
    wr[gid] = f2bf(w[(size_t)o*1152 + i*3 + k]);
  }
}

// ---------------- conv2 as MFMA GEMM: M=8192, N=384, K=576 (3 taps x 192 ch, stride 2) ----------------
__global__ __launch_bounds__(256) void conv2_mfma(const unsigned short* __restrict__ A,   // T1 [16384][192]
                                                  const unsigned short* __restrict__ W,   // w2r [384][576]
                                                  const float* __restrict__ bias,
                                                  const float* __restrict__ g, const float* __restrict__ bb,
                                                  const float* __restrict__ bm, const float* __restrict__ bv,
                                                  unsigned short* __restrict__ outb){     // T2 [8192][384]
  __shared__ unsigned short As[4096], Bs[4096];
  const int tid = threadIdx.x;
  const int lane = tid & 63, wave = tid >> 6;
  const int wm = wave & 1, wn = wave >> 1;
  const int m0 = blockIdx.y*128, n0 = blockIdx.x*128;
  const int bidx = m0 >> 10, tloc = m0 & 1023;
  f32x4 acc[4][4];
  #pragma unroll
  for(int i=0;i<4;++i)
    #pragma unroll
    for(int j=0;j<4;++j) acc[i][j] = (f32x4){0.f,0.f,0.f,0.f};
  const int u0 = tid, u1 = tid + 256;
  const int r0 = u0>>2, kl0 = (u0&3) ^ ((r0>>1)&3);
  const int r1 = u1>>2, kl1 = (u1&3) ^ ((r1>>1)&3);
  const int kg = lane>>4, ml = lane&15;
  const short8 z8 = {0,0,0,0,0,0,0,0};
  for(int kb=0; kb<3; ++kb){
    int ta = 2*(tloc + r0) + kb - 1;
    int tb = 2*(tloc + r1) + kb - 1;
    bool va = (ta>=0) && (ta<2048);
    bool vb = (tb>=0) && (tb<2048);
    const unsigned short* pa = A + ((size_t)bidx*2048 + ta)*192;
    const unsigned short* pb = A + ((size_t)bidx*2048 + tb)*192;
    for(int c0=0; c0<192; c0+=32){
      int k0 = kb*192 + c0;
      short8 a0 = va ? *reinterpret_cast<const short8*>(pa + c0 + kl0*8) : z8;
      short8 a1 = vb ? *reinterpret_cast<const short8*>(pb + c0 + kl1*8) : z8;
      short8 b0 = *reinterpret_cast<const short8*>(W + (size_t)(n0+r0)*576 + k0 + kl0*8);
      short8 b1 = *reinterpret_cast<const short8*>(W + (size_t)(n0+r1)*576 + k0 + kl1*8);
      __syncthreads();
      *reinterpret_cast<short8*>(As + u0*8) = a0;
      *reinterpret_cast<short8*>(As + u1*8) = a1;
      *reinterpret_cast<short8*>(Bs + u0*8) = b0;
      *reinterpret_cast<short8*>(Bs + u1*8) = b1;
      __syncthreads();
      short8 af[4], bfr[4];
      #pragma unroll
      for(int f=0;f<4;++f){
        int row = wm*64 + f*16 + ml;
        int un  = row*4 + (kg ^ ((row>>1)&3));
        af[f] = *reinterpret_cast<const short8*>(As + un*8);
        int rowb = wn*64 + f*16 + ml;
        int ub   = rowb*4 + (kg ^ ((rowb>>1)&3));
        bfr[f] = *reinterpret_cast<const short8*>(Bs + ub*8);
      }
      #pragma unroll
      for(int i=0;i<4;++i)
        #pragma unroll
        for(int j=0;j<4;++j)
          acc[i][j] = __builtin_amdgcn_mfma_f32_16x16x32_bf16(af[i], bfr[j], acc[i][j], 0, 0, 0);
    }
  }
  #pragma unroll
  for(int i=0;i<4;++i){
    int rb = m0 + wm*64 + i*16 + kg*4;
    #pragma unroll
    for(int j=0;j<4;++j){
      int col = n0 + wn*64 + j*16 + ml;
      float sc = g[col]*rsqrtf(bv[col]+1e-5f);
      float mm = bm[col], bbv = bb[col], bi = bias[col];
      #pragma unroll
      for(int r=0;r<4;++r){
        float yv = geluf(acc[i][j][r] + bi);
        yv = (yv - mm)*sc + bbv;
        outb[(size_t)(rb+r)*384 + col] = f2bf(yv);
      }
    }
  }
}

// ---------------- conv3 as MFMA GEMM: M=8192, N=768, K=1152 (3 taps x 384 ch, stride 1) ----------------
__global__ __launch_bounds__(256) void conv3_mfma(const unsigned short* __restrict__ A,   // T2 [8192][384]
                                                  const unsigned short* __restrict__ W,   // w3r [768][1152]
                                                  const float* __restrict__ bias,
                                                  const float* __restrict__ g, const float* __restrict__ bb,
                                                  const float* __restrict__ bm, const float* __restrict__ bv,
                                                  unsigned short* __restrict__ outb,      // h3t bf16 [8192][768]
                                                  float* __restrict__ outf){              // h3f fp32 [8192][768]
  __shared__ unsigned short As[4096], Bs[4096];
  const int tid = threadIdx.x;
  const int lane = tid & 63, wave = tid >> 6;
  const int wm = wave & 1, wn = wave >> 1;
  const int m0 = blockIdx.y*128, n0 = blockIdx.x*128;
  const int bidx = m0 >> 10, tloc = m0 & 1023;
  f32x4 acc[4][4];
  #pragma unroll
  for(int i=0;i<4;++i)
    #pragma unroll
    for(int j=0;j<4;++j) acc[i][j] = (f32x4){0.f,0.f,0.f,0.f};
  const int u0 = tid, u1 = tid + 256;
  const int r0 = u0>>2, kl0 = (u0&3) ^ ((r0>>1)&3);
  const int r1 = u1>>2, kl1 = (u1&3) ^ ((r1>>1)&3);
  const int kg = lane>>4, ml = lane&15;
  const short8 z8 = {0,0,0,0,0,0,0,0};
  for(int kb=0; kb<3; ++kb){
    int ta = tloc + r0 + kb - 1;
    int tb = tloc + r1 + kb - 1;
    bool va = (ta>=0) && (ta<1024);
    bool vb = (tb>=0) && (tb<1024);
    const unsigned short* pa = A + ((size_t)bidx*1024 + ta)*384;
    const unsigned short* pb = A + ((size_t)bidx*1024 + tb)*384;
    for(int c0=0; c0<384; c0+=32){
      int k0 = kb*384 + c0;
      short8 a0 = va ? *reinterpret_cast<const short8*>(pa + c0 + kl0*8) : z8;
      short8 a1 = vb ? *reinterpret_cast<const short8*>(pb + c0 + kl1*8) : z8;
      short8 b0 = *reinterpret_cast<const short8*>(W + (size_t)(n0+r0)*1152 + k0 + kl0*8);
      short8 b1 = *reinterpret_cast<const short8*>(W + (size_t)(n0+r1)*1152 + k0 + kl1*8);
      __syncthreads();
      *reinterpret_cast<short8*>(As + u0*8) = a0;
      *reinterpret_cast<short8*>(As + u1*8) = a1;
      *reinterpret_cast<short8*>(Bs + u0*8) = b0;
      *reinterpret_cast<short8*>(Bs + u1*8) = b1;
      __syncthreads();
      short8 af[4], bfr[4];
      #pragma unroll
      for(int f=0;f<4;++f){
        int row = wm*64 + f*16 + ml;
        int un  = row*4 + (kg ^ ((row>>1)&3));
        af[f] = *reinterpret_cast<const short8*>(As + un*8);
        int rowb = wn*64 + f*16 + ml;
        int ub   = rowb*4 + (kg ^ ((rowb>>1)&3));
        bfr[f] = *reinterpret_cast<const short8*>(Bs + ub*8);
      }
      #pragma unroll
      for(int i=0;i<4;++i)
        #pragma unroll
        for(int j=0;j<4;++j)
          acc[i][j] = __builtin_amdgcn_mfma_f32_16x16x32_bf16(af[i], bfr[j], acc[i][j], 0, 0, 0);
    }
  }
  #pragma unroll
  for(int i=0;i<4;++i){
    int rb = m0 + wm*64 + i*16 + kg*4;
    #pragma unroll
    for(int j=0;j<4;++j){
      int col = n0 + wn*64 + j*16 + ml;
      float sc = g[col]*rsqrtf(bv[col]+1e-5f);
      float mm = bm[col], bbv = bb[col], bi = bias[col];
      #pragma unroll
      for(int r=0;r<4;++r){
        float yv = geluf(acc[i][j][r] + bi);
        yv = (yv - mm)*sc + bbv;
        outb[(size_t)(rb+r)*768 + col] = f2bf(yv);
        outf[(size_t)(rb+r)*768 + col] = yv;
      }
    }
  }
}

// ---------------- W rows 0..3327 fp32 -> bf16 (in_proj) ----------------
__global__ void wconv_k(const float* __restrict__ W, unsigned short* __restrict__ Wb){
  int i = (blockIdx.x*256 + threadIdx.x)*4;
  if(i < 2555904){
    float4 v = *reinterpret_cast<const float4*>(&W[i]);
    Wb[i+0] = f2bf(v.x); Wb[i+1] = f2bf(v.y); Wb[i+2] = f2bf(v.z); Wb[i+3] = f2bf(v.w);
  }
}

// ---------------- in_proj MFMA: out[m][n] = sum_k A[m][k]*W[n][k]; M=8192 N=3328 K=768 ----------------
__global__ __launch_bounds__(256) void inproj_mfma(const unsigned short* __restrict__ A,
                                                   const unsigned short* __restrict__ B,
                                                   float* __restrict__ out){
  __shared__ unsigned short As[4096], Bs[4096];
  const int tid = threadIdx.x;
  const int lane = tid & 63, wave = tid >> 6;
  const int wm = wave & 1, wn = wave >> 1;
  const int m0 = blockIdx.y*128, n0 = blockIdx.x*128;
  f32x4 acc[4][4];
  #pragma unroll
  for(int i=0;i<4;++i)
    #pragma unroll
    for(int j=0;j<4;++j) acc[i][j] = (f32x4){0.f,0.f,0.f,0.f};
  const int u0 = tid, u1 = tid + 256;
  const int r0 = u0>>2, kl0 = (u0&3) ^ ((r0>>1)&3);
  const int r1 = u1>>2, kl1 = (u1&3) ^ ((r1>>1)&3);
  const int kg = lane>>4, ml = lane&15;
  for(int k0=0;k0<768;k0+=32){
    short8 a0 = *reinterpret_cast<const short8*>(A + (size_t)(m0+r0)*768 + k0 + kl0*8);
    short8 a1 = *reinterpret_cast<const short8*>(A + (size_t)(m0+r1)*768 + k0 + kl1*8);
    short8 b0 = *reinterpret_cast<const short8*>(B + (size_t)(n0+r0)*768 + k0 + kl0*8);
    short8 b1 = *reinterpret_cast<const short8*>(B + (size_t)(n0+r1)*768 + k0 + kl1*8);
    __syncthreads();
    *reinterpret_cast<short8*>(As + u0*8) = a0;
    *reinterpret_cast<short8*>(As + u1*8) = a1;
    *reinterpret_cast<short8*>(Bs + u0*8) = b0;
    *reinterpret_cast<short8*>(Bs + u1*8) = b1;
    __syncthreads();
    short8 af[4], bfr[4];
    #pragma unroll
    for(int f=0;f<4;++f){
      int row = wm*64 + f*16 + ml;
      int un  = row*4 + (kg ^ ((row>>1)&3));
      af[f] = *reinterpret_cast<const short8*>(As + un*8);
      int rowb = wn*64 + f*16 + ml;
      int ub   = rowb*4 + (kg ^ ((rowb>>1)&3));
      bfr[f] = *reinterpret_cast<const short8*>(Bs + ub*8);
    }
    #pragma unroll
    for(int i=0;i<4;++i)
      #pragma unroll
      for(int j=0;j<4;++j)
        acc[i][j] = __builtin_amdgcn_mfma_f32_16x16x32_bf16(af[i], bfr[j], acc[i][j], 0, 0, 0);
  }
  #pragma unroll
  for(int i=0;i<4;++i){
    int rb = m0 + wm*64 + i*16 + kg*4;
    #pragma unroll
    for(int j=0;j<4;++j){
      int col = n0 + wn*64 + j*16 + ml;
      #pragma unroll
      for(int r=0;r<4;++r)
        out[(size_t)(rb+r)*3340 + col] = acc[i][j][r];
    }
  }
}

// ---------------- dt GEMM (fp32, row-major h3) + softplus + dA, fused ----------------
__global__ __launch_bounds__(256) void dtgemm2_k(const float* __restrict__ h3f, const float* __restrict__ W,
                                                 const float* __restrict__ dt_bias, const float* __restrict__ A_log,
                                                 float* __restrict__ dt, float* __restrict__ dA){
  __shared__ float Ws[12][768];
  __shared__ float Ah[12], Bh[12];
  int tid = threadIdx.x;
  for(int idx=tid; idx<9216; idx+=256){
    int hh = idx/768, k = idx - hh*768;
    Ws[hh][k] = W[(size_t)(3328+hh)*768 + k];
  }
  if(tid<12){ Ah[tid] = -expf(A_log[tid]); Bh[tid] = dt_bias[tid]; }
  __syncthreads();
  int wave = tid>>6, lane = tid&63;
  int m = blockIdx.x*4 + wave;
  const float* xr = h3f + (size_t)m*768;
  float xv[12];
  #pragma unroll
  for(int q=0;q<12;++q) xv[q] = xr[q*64+lane];
  float res[12];
  #pragma unroll
  for(int h=0;h<12;++h){
    float acc = 0.f;
    #pragma unroll
    for(int q=0;q<12;++q) acc = fmaf(xv[q], Ws[h][q*64+lane], acc);
    #pragma unroll
    for(int off=32;off;off>>=1) acc += __shfl_xor(acc, off);
    res[h] = acc;
  }
  if(lane==0){
    #pragma unroll
    for(int h=0;h<12;++h){
      float sp = softplusf(res[h] + Bh[h]);
      dt[(size_t)m*12+h] = sp;
      dA[(size_t)m*12+h] = expf(sp*Ah[h]);
    }
  }
}

// ---------------- depthwise causal conv k=4 + silu + split ----------------
__global__ void dwconv_k(const float* __restrict__ zx, const float* __restrict__ cw,
                         const float* __restrict__ cb, float* __restrict__ xs,
                         float* __restrict__ Bo, float* __restrict__ Co){
  int gid = blockIdx.x*256 + threadIdx.x;
  int c = gid % 1792;
  int m = gid / 1792;
  int t = m & 1023;
  float4 w4 = *reinterpret_cast<const float4*>(&cw[c*4]);
  float wv[4] = {w4.x,w4.y,w4.z,w4.w};
  float acc = cb[c];
  #pragma unroll
  for(int j=0;j<4;++j){
    int tt = t - 3 + j;
    if(tt >= 0) acc = fmaf(wv[j], zx[(size_t)(m-3+j)*3340 + 1536 + c], acc);
  }
  float val = siluf(acc);
  if(c < 1536)       xs[(size_t)m*1536 + c]        = val;
  else if(c < 1664)  Bo[(size_t)m*128 + (c-1536)]  = val;
  else               Co[(size_t)m*128 + (c-1664)]  = val;
}

// ---------------- per-chunk inclusive cumprod of dA ----------------
__global__ void cumda_k(const float* __restrict__ dA, float* __restrict__ cda){
  __shared__ float ld[1024];
  int bh = blockIdx.x; int b = bh/12, hh = bh - b*12;
  int tid = threadIdx.x;
  for(int i=tid;i<1024;i+=128) ld[i] = dA[((size_t)b*1024 + i)*12 + hh];
  __syncthreads();
  for(int c=0;c<8;++c){
    int base = c*128;
    for(int off=1;off<128;off<<=1){
      float v = ld[base+tid];
      if(tid>=off) v *= ld[base+tid-off];
      __syncthreads();
      ld[base+tid] = v;
      __syncthreads();
    }
  }
  for(int i=tid;i<1024;i+=128) cda[(size_t)bh*1024 + i] = ld[i];
}

// ---------------- SSM scan pass 1: per-chunk local scan (in-place ys over xs) ----------------
#define SSTEP(E, BQE, CQE) \
  s[0][jj*4+E] = fmaf(s[0][jj*4+E], dav, c0*BQE); y0 = fmaf(s[0][jj*4+E], CQE, y0); \
  s[1][jj*4+E] = fmaf(s[1][jj*4+E], dav, c1*BQE); y1 = fmaf(s[1][jj*4+E], CQE, y1); \
  s[2][jj*4+E] = fmaf(s[2][jj*4+E], dav, c2*BQE); y2 = fmaf(s[2][jj*4+E], CQE, y2); \
  s[3][jj*4+E] = fmaf(s[3][jj*4+E], dav, c3*BQE); y3 = fmaf(s[3][jj*4+E], CQE, y3);

__global__ __launch_bounds__(128) void scan_chunk_k(float* __restrict__ xs,
    const float* __restrict__ Bm, const float* __restrict__ Cm,
    const float* __restrict__ dtb, const float* __restrict__ dAb,
    const float* __restrict__ Dv, float* __restrict__ sfin){
  const int c = blockIdx.x, h = blockIdx.y, b = blockIdx.z;
  const int tid = threadIdx.x;
  const int ng = tid & 3, pg = tid >> 2;
  __shared__ float lx[16][128], lB[16][144], lC[16][144], ly[16][128];
  __shared__ float ldt[16], lda_[16];
  float s[4][32];
  #pragma unroll
  for(int i=0;i<4;++i)
    #pragma unroll
    for(int j=0;j<32;++j) s[i][j]=0.f;
  const float Dh = Dv[h];
  const size_t mb = (size_t)b*1024 + (size_t)c*128;
  for(int t0=0;t0<128;t0+=16){
    for(int idx=tid; idx<2048; idx+=128){
      int tl = idx>>7, cc = idx&127;
      lx[tl][cc] = xs[(mb+t0+tl)*1536 + h*128 + cc];
      int slot = (cc>>5)*36 + (cc&31);
      lB[tl][slot] = Bm[(mb+t0+tl)*128 + cc];
      lC[tl][slot] = Cm[(mb+t0+tl)*128 + cc];
    }
    if(tid<16){
      ldt[tid]  = dtb[(mb+t0+tid)*12 + h];
      lda_[tid] = dAb[(mb+t0+tid)*12 + h];
    }
    __syncthreads();
    for(int tl=0; tl<16; ++tl){
      float dtv = ldt[tl], dav = lda_[tl];
      float4 xq = *reinterpret_cast<const float4*>(&lx[tl][pg*4]);
      float c0 = dtv*xq.x, c1 = dtv*xq.y, c2 = dtv*xq.z, c3 = dtv*xq.w;
      float y0=0.f,y1=0.f,y2=0.f,y3=0.f;
      #pragma unroll
      for(int jj=0;jj<8;++jj){
        float4 bq = *reinterpret_cast<const float4*>(&lB[tl][ng*36+jj*4]);
        float4 cq = *reinterpret_cast<const float4*>(&lC[tl][ng*36+jj*4]);
        SSTEP(0, bq.x, cq.x)
        SSTEP(1, bq.y, cq.y)
        SSTEP(2, bq.z, cq.z)
        SSTEP(3, bq.w, cq.w)
      }
      y0 += __shfl_xor(y0,1); y0 += __shfl_xor(y0,2);
      y1 += __shfl_xor(y1,1); y1 += __shfl_xor(y1,2);
      y2 += __shfl_xor(y2,1); y2 += __shfl_xor(y2,2);
      y3 += __shfl_xor(y3,1); y3 += __shfl_xor(y3,2);
      if(ng==0) *reinterpret_cast<float4*>(&ly[tl][pg*4]) = make_float4(y0,y1,y2,y3);
    }
    __syncthreads();
    for(int idx=tid; idx<2048; idx+=128){
      int tl = idx>>7, cc = idx&127;
      xs[(mb+t0+tl)*1536 + h*128 + cc] = ly[tl][cc] + Dh*lx[tl][cc];
    }
    __syncthreads();
  }
  float* dst = sfin + ((size_t)(b*12+h)*8 + c)*16384;
  #pragma unroll
  for(int jj=0;jj<8;++jj)
    #pragma unroll
    for(int e=0;e<4;++e){
      int n = ng*32 + jj*4 + e;
      *reinterpret_cast<float4*>(&dst[(size_t)n*128 + pg*4]) =
        make_float4(s[0][jj*4+e], s[1][jj*4+e], s[2][jj*4+e], s[3][jj*4+e]);
    }
}

// ---------------- SSM scan pass 2: inter-chunk correction y += cumP * (C . S_init) ----------------
__global__ __launch_bounds__(256) void correct_k(const float* __restrict__ Cm,
    const float* __restrict__ cumdA, const float* __restrict__ sfin,
    float* __restrict__ ys){
  const int c = blockIdx.x + 1, h = blockIdx.y, b = blockIdx.z;
  const int tid = threadIdx.x;
  const size_t bh = (size_t)b*12 + h;
  __shared__ float Sl[16][128];
  __shared__ float Cl[16][132];
  __shared__ float cumP[128];
  __shared__ float coefs[8];
  if(tid==0){
    float cf = 1.f;
    for(int cp=c-1; cp>=0; --cp){
      coefs[cp] = cf;
      cf *= cumdA[bh*1024 + (size_t)cp*128 + 127];
    }
  }
  if(tid<128) cumP[tid] = cumdA[bh*1024 + (size_t)c*128 + tid];
  __syncthreads();
  const int tp = tid>>4, tt = tid&15;
  float acc[8][8];
  #pragma unroll
  for(int i=0;i<8;++i)
    #pragma unroll
    for(int j=0;j<8;++j) acc[i][j]=0.f;
  const size_t mb = (size_t)b*1024 + (size_t)c*128;
  for(int n0=0;n0<128;n0+=16){
    {
      int kk = tid>>4, po = tid&15;
      float4 v0 = {0,0,0,0}, v1 = {0,0,0,0};
      for(int cp=0; cp<c; ++cp){
        const float* sp = sfin + ((bh*8 + cp)*16384) + (size_t)(n0+kk)*128 + po*8;
        float4 a0 = *reinterpret_cast<const float4*>(sp);
        float4 a1 = *reinterpret_cast<const float4*>(sp+4);
        float cf = coefs[cp];
        v0.x = fmaf(cf,a0.x,v0.x); v0.y = fmaf(cf,a0.y,v0.y);
        v0.z = fmaf(cf,a0.z,v0.z); v0.w = fmaf(cf,a0.w,v0.w);
        v1.x = fmaf(cf,a1.x,v1.x); v1.y = fmaf(cf,a1.y,v1.y);
        v1.z = fmaf(cf,a1.z,v1.z); v1.w = fmaf(cf,a1.w,v1.w);
      }
      *reinterpret_cast<float4*>(&Sl[kk][po*8])   = v0;
      *reinterpret_cast<float4*>(&Sl[kk][po*8+4]) = v1;
    }
    #pragma unroll
    for(int e=0;e<8;++e){
      int idx = tid*8 + e; int tl = idx>>4, kk = idx&15;
      Cl[kk][tl] = Cm[(mb + tl)*128 + n0 + kk];
    }
    __syncthreads();
    #pragma unroll
    for(int kk=0;kk<16;++kk){
      float4 sa = *reinterpret_cast<const float4*>(&Sl[kk][tp*8]);
      float4 sb = *reinterpret_cast<const float4*>(&Sl[kk][tp*8+4]);
      float4 ca = *reinterpret_cast<const float4*>(&Cl[kk][tt*8]);
      float4 cb = *reinterpret_cast<const float4*>(&Cl[kk][tt*8+4]);
      float sv[8] = {sa.x,sa.y,sa.z,sa.w,sb.x,sb.y,sb.z,sb.w};
      float cv[8] = {ca.x,ca.y,ca.z,ca.w,cb.x,cb.y,cb.z,cb.w};
      #pragma unroll
      for(int i=0;i<8;++i)
        #pragma unroll
        for(int j=0;j<8;++j) acc[i][j] = fmaf(sv[i], cv[j], acc[i][j]);
    }
    __syncthreads();
  }
  #pragma unroll
  for(int j=0;j<8;++j){
    int tl = tt*8 + j;
    float cp = cumP[tl];
    float* yp = ys + (mb + tl)*1536 + h*128 + tp*8;
    float4 y0 = *reinterpret_cast<float4*>(yp);
    float4 y1 = *reinterpret_cast<float4*>(yp+4);
    y0.x += cp*acc[0][j]; y0.y += cp*acc[1][j]; y0.z += cp*acc[2][j]; y0.w += cp*acc[3][j];
    y1.x += cp*acc[4][j]; y1.y += cp*acc[5][j]; y1.z += cp*acc[6][j]; y1.w += cp*acc[7][j];
    *reinterpret_cast<float4*>(yp)   = y0;
    *reinterpret_cast<float4*>(yp+4) = y1;
  }
}

// ---------------- gating: y*silu(z), RMSNorm, partitioned mean-accumulate ----------------
__global__ void gate_k(const float* __restrict__ ys, const float* __restrict__ zx,
                       const float* __restrict__ nw, float* __restrict__ ybp){
  int m = blockIdx.x;
  int b = m >> 10, t = m & 1023;
  int tid = threadIdx.x;
  float gvals[6];
  float ss = 0.0f;
  #pragma unroll
  for(int r=0;r<6;++r){
    int c = r*256 + tid;
    float yv = ys[(size_t)m*1536 + c];
    float zv = zx[(size_t)m*3340 + c];
    float gv = yv * siluf(zv);
    gvals[r] = gv;
    ss = fmaf(gv, gv, ss);
  }
  #pragma unroll
  for(int off=32;off;off>>=1) ss += __shfl_xor(ss, off);
  __shared__ float red[4];
  if((tid&63)==0) red[tid>>6] = ss;
  __syncthreads();
  float tot = red[0]+red[1]+red[2]+red[3];
  float scale = rsqrtf(tot*(1.0f/1536.0f) + 1e-5f);
  float* dst = ybp + ((size_t)(t&7)*8 + b)*1536;
  #pragma unroll
  for(int r=0;r<6;++r){
    int c = r*256 + tid;
    atomicAdd(&dst[c], gvals[r]*scale*nw[c]);
  }
}

__global__ void ybm_k(const float* __restrict__ ybp, float* __restrict__ ybm){
  int idx = blockIdx.x*256 + threadIdx.x;
  float s = 0.0f;
  #pragma unroll
  for(int p=0;p<8;++p) s += ybp[(size_t)p*12288 + idx];
  ybm[idx] = s * (1.0f/1024.0f);
}

__global__ void rep_k(const float* __restrict__ ybm, const float* __restrict__ W,
                      float* __restrict__ rep){
  int wid  = (blockIdx.x<<2) + (threadIdx.x>>6);
  int lane = threadIdx.x & 63;
  int b = wid / 768, o = wid % 768;
  const float* xr = ybm + (size_t)b*1536;
  const float* wr = W + (size_t)o*1536;
  float acc = 0.0f;
  for(int c=lane;c<1536;c+=64) acc = fmaf(xr[c], wr[c], acc);
  #pragma unroll
  for(int off=32;off;off>>=1) acc += __shfl_xor(acc, off);
  if(lane==0) rep[wid] = acc;
}

__global__ void fc1_k(const float* __restrict__ rep, const float* __restrict__ W,
                      const float* __restrict__ bias, const float* __restrict__ g,
                      const float* __restrict__ bb, const float* __restrict__ m,
                      const float* __restrict__ v, float* __restrict__ out){
  int wid  = (blockIdx.x<<2) + (threadIdx.x>>6);
  int lane = threadIdx.x & 63;
  int b = wid >> 10, o = wid & 1023;
  const float* xr = rep + (size_t)b*768;
  const float* wr = W + (size_t)o*768;
  float acc = 0.0f;
  for(int c=lane;c<768;c+=64) acc = fmaf(xr[c], wr[c], acc);
  #pragma unroll
  for(int off=32;off;off>>=1) acc += __shfl_xor(acc, off);
  if(lane==0){
    float val = acc + bias[o];
    float sc = g[o]*rsqrtf(v[o]+1e-5f);
    val = (val - m[o])*sc + bb[o];
    out[wid] = fmaxf(val, 0.0f);
  }
}

__global__ void fc2_k(const float* __restrict__ h1, const float* __restrict__ W,
                      const float* __restrict__ bias, float* __restrict__ out){
  int wid  = (blockIdx.x<<2) + (threadIdx.x>>6);
  int lane = threadIdx.x & 63;
  int b = wid / 27, o = wid % 27;
  const float* xr = h1 + (size_t)b*1024;
  const float* wr = W + (size_t)o*1024;
  float acc = 0.0f;
  for(int c=lane;c<1024;c+=64) acc = fmaf(xr[c], wr[c], acc);
  #pragma unroll
  for(int off=32;off;off>>=1) acc += __shfl_xor(acc, off);
  if(lane==0) out[wid] = acc + bias[o];
}

// ---------------- workspace layout (float offsets) ----------------
// Footprint identical to the proven round-4 run: 54,945,792 floats (219.78 MB).
// Early region [0, 12,582,912) holds the conv pipeline temporaries (all dead
// before sfin overlays at 0). h3f borrows the XS slot (dead before dwconv).
#define OFF_H1     0u           // 3,145,728 fp32  [conv1 -> xpose1]
#define OFF_T1     3145728u     // 1,572,864 (ushort x 3,145,728) [xpose1 -> conv2]
#define OFF_T2     4718592u     // 1,572,864 [conv2 -> conv3]
#define OFF_H3T    6291456u     // 3,145,728 (ushort x 6,291,456) [conv3 -> inproj]
#define OFF_WB     9437184u     // 1,277,952 [wconv -> inproj]
#define OFF_W2R    10715136u    // 110,592
#define OFF_W3R    10825728u    // 442,368 ; early region ends 11,268,096
#define OFF_ZX     12582912u    // 27,361,280
#define OFF_XS     39944192u    // 12,582,912 (h3f first, then xs/ys)
#define OFF_H3F    39944192u    // 6,291,456 fp32 [conv3 -> dtgemm2, before dwconv]
#define OFF_B      52527104u    // 1,048,576
#define OFF_C      53575680u    // 1,048,576
#define OFF_DT     54624256u    // 98,304
#define OFF_DA     54722560u    // 98,304
#define OFF_SLOT98K 54820864u   // 98,304: cda -> ybp (sequential lifetimes)
#define OFF_YBM    54919168u    // 12,288
#define OFF_REP    54931456u    // 6,144
#define OFF_FC1    54937600u    // 8,192 ; end = 54,945,792
#define OFF_SFIN   0u           // 12,582,912 [scan -> correct], early region dead

extern "C" void kernel_launch(void* const* d_in, const int* in_sizes, int n_in,
                              void* d_out, int out_size, void* d_ws, size_t ws_size,
                              hipStream_t stream){
  const float* x       = (const float*)d_in[0];
  const float* w1      = (const float*)d_in[1];
  const float* b1      = (const float*)d_in[2];
  const float* bn1g    = (const float*)d_in[3];
  const float* bn1b    = (const float*)d_in[4];
  const float* bn1m    = (const float*)d_in[5];
  const float* bn1v    = (const float*)d_in[6];
  const float* w2      = (const float*)d_in[7];
  const float* b2      = (const float*)d_in[8];
  const float* bn2g    = (const float*)d_in[9];
  const float* bn2b    = (const float*)d_in[10];
  const float* bn2m    = (const float*)d_in[11];
  const float* bn2v    = (const float*)d_in[12];
  const float* w3      = (const float*)d_in[13];
  const float* b3      = (const float*)d_in[14];
  const float* bn3g    = (const float*)d_in[15];
  const float* bn3b    = (const float*)d_in[16];
  const float* bn3m    = (const float*)d_in[17];
  const float* bn3v    = (const float*)d_in[18];
  const float* ipw     = (const float*)d_in[19];
  const float* convw   = (const float*)d_in[20];
  const float* convb   = (const float*)d_in[21];
  const float* dtbias  = (const float*)d_in[22];
  const float* Alog    = (const float*)d_in[23];
  const float* Dvec    = (const float*)d_in[24];
  const float* normw   = (const float*)d_in[25];
  const float* opw     = (const float*)d_in[26];
  const float* fc1w    = (const float*)d_in[27];
  const float* fc1b    = (const float*)d_in[28];
  const float* bncg    = (const float*)d_in[29];
  const float* bncb    = (const float*)d_in[30];
  const float* bncm    = (const float*)d_in[31];
  const float* bncv    = (const float*)d_in[32];
  const float* fc2w    = (const float*)d_in[33];
  const float* fc2b    = (const float*)d_in[34];

  float* ws   = (float*)d_ws;
  float* h1   = ws + OFF_H1;
  unsigned short* T1  = (unsigned short*)(ws + OFF_T1);
  unsigned short* T2  = (unsigned short*)(ws + OFF_T2);
  unsigned short* h3t = (unsigned short*)(ws + OFF_H3T);
  unsigned short* Wb  = (unsigned short*)(ws + OFF_WB);
  unsigned short* w2r = (unsigned short*)(ws + OFF_W2R);
  unsigned short* w3r = (unsigned short*)(ws + OFF_W3R);
  float* zx   = ws + OFF_ZX;
  float* xsb  = ws + OFF_XS;
  float* h3f  = ws + OFF_H3F;
  float* Bb   = ws + OFF_B;
  float* Cb   = ws + OFF_C;
  float* dtb  = ws + OFF_DT;
  float* dAb  = ws + OFF_DA;
  float* slot = ws + OFF_SLOT98K;
  float* ybm  = ws + OFF_YBM;
  float* rep  = ws + OFF_REP;
  float* f1b  = ws + OFF_FC1;
  float* sfin = ws + OFF_SFIN;
  float* outp = (float*)d_out;

  conv1_k<<<dim3(8,24,8),  256, 0, stream>>>(x, w1, b1, bn1g, bn1b, bn1m, bn1v, h1);
  xpose1_k<<<dim3(64,6,8), 256, 0, stream>>>(h1, T1);
  wconv_k<<<2496, 256, 0, stream>>>(ipw, Wb);
  wr2_k<<<864, 256, 0, stream>>>(w2, w2r);
  wr3_k<<<3456, 256, 0, stream>>>(w3, w3r);
  conv2_mfma<<<dim3(3,64), 256, 0, stream>>>(T1, w2r, b2, bn2g, bn2b, bn2m, bn2v, T2);
  conv3_mfma<<<dim3(6,64), 256, 0, stream>>>(T2, w3r, b3, bn3g, bn3b, bn3m, bn3v, h3t, h3f);
  dtgemm2_k<<<2048, 256, 0, stream>>>(h3f, ipw, dtbias, Alog, dtb, dAb);
  inproj_mfma<<<dim3(26,64), 256, 0, stream>>>(h3t, Wb, zx);
  dwconv_k<<<57344, 256, 0, stream>>>(zx, convw, convb, xsb, Bb, Cb);
  cumda_k<<<96, 128, 0, stream>>>(dAb, slot);                        // cda = slot
  scan_chunk_k<<<dim3(8,12,8), 128, 0, stream>>>(xsb, Bb, Cb, dtb, dAb, Dvec, sfin);
  correct_k<<<dim3(7,12,8), 256, 0, stream>>>(Cb, slot, sfin, xsb);  // reads cda
  hipMemsetAsync(slot, 0, 98304*sizeof(float), stream);              // zero ybp
  gate_k<<<8192, 256, 0, stream>>>(xsb, zx, normw, slot);            // ybp = slot
  ybm_k<<<48, 256, 0, stream>>>(slot, ybm);
  rep_k<<<1536, 256, 0, stream>>>(ybm, opw, rep);
  fc1_k<<<2048, 256, 0, stream>>>(rep, fc1w, fc1b, bncg, bncb, bncm, bncv, f1b);
  fc2_k<<<54, 256, 0, stream>>>(f1b, fc2w, fc2b, outp);
}